// Round 11
// baseline (342.375 us; speedup 1.0000x reference)
//
#include <hip/hip_runtime.h>
#include <hip/hip_bf16.h>

#define NN 16
#define CC 256
#define TT 64
#define VV 25
#define ICC 64
#define TV 1600      // TT*VV
#define CTV 409600   // CC*TV
#define NICTV 1638400  // elements per f-slice: 16*1600*64

typedef __bf16 v8bf __attribute__((ext_vector_type(8)));
typedef __bf16 v4bf __attribute__((ext_vector_type(4)));
typedef float f32x16 __attribute__((ext_vector_type(16)));

struct ConvPairs {
  const __bf16* wA[5];
  const __bf16* wB[5];
  const float*  bA[5];
  const float*  bB[5];
};

__device__ __forceinline__ void gl_lds16(const __bf16* g, __bf16* l){
  __builtin_amdgcn_global_load_lds(
      (const __attribute__((address_space(1))) unsigned int*)g,
      (__attribute__((address_space(3))) unsigned int*)l, 16, 0, 0);
}

// ---------- merged prep: sections by blockIdx.x
// [0,64)     pack 9-tap weights fragment-linear (CW=32):
//            per conv layout: [(ch8*9+tap)*2+ks][o2][lane64][e8] bf16
// [64,74)    pack 1x1 weights (CW=32): [(ch8*2+ks)][o2][lane64][e8]
// [74,842)   wd -> bf16
// [842]      a_all + zero-page
// [843,2443) xt: x -> channels-last bf16
__global__ __launch_bounds__(256) void prep_k(
    const float* __restrict__ x, __bf16* __restrict__ xt,
    const float* __restrict__ wT1, const float* __restrict__ wT2,
    const float* __restrict__ wST11, const float* __restrict__ wST12,
    __bf16* __restrict__ wT1p, __bf16* __restrict__ wT2p,
    __bf16* __restrict__ wS1p, __bf16* __restrict__ wS2p,
    const float* __restrict__ wa, const float* __restrict__ wb,
    __bf16* __restrict__ wabp, __bf16* __restrict__ wScp,
    const float* __restrict__ wd, __bf16* __restrict__ wdb,
    const float* __restrict__ A, const float* __restrict__ PA,
    float* __restrict__ Aall, __bf16* __restrict__ zp){
  __shared__ __align__(16) float smf[64*65];
  __bf16* smb = (__bf16*)smf;
  int b = blockIdx.x;
  int tid = threadIdx.x;
  if (b < 64){
    // 9-tap fragment packing. t: 0-2 wT1 s, 3-5 wT2 s, 6 wST11 s=1, 7 wST12 s=1
    int t = b >> 3, ch64 = (b >> 1) & 3, o2 = b & 1;
    const float* src; __bf16* dst;
    if (t < 3)      { src = wT1  + (size_t)t*147456;     dst = wT1p + (size_t)t*147456; }
    else if (t < 6) { src = wT2  + (size_t)(t-3)*147456; dst = wT2p + (size_t)(t-3)*147456; }
    else if (t == 6){ src = wST11 + 147456;              dst = wS1p; }
    else            { src = wST12 + 147456;              dst = wS2p; }
    const float* in = src + (size_t)(o2*32)*2304 + ch64*576;
    // stage 32 o-rows x 576 f32 (64 ch x 9 taps) as bf16
    for (int i = tid; i < 32*576; i += 256){
      int row = i / 576, cc = i % 576;
      smb[i] = (__bf16)in[(size_t)row*2304 + cc];
    }
    __syncthreads();
    // emit: chhalf(2) x tap(9) x ks(2) x lane(64) x e(8) = 18432
    for (int i = tid; i < 18432; i += 256){
      int e = i & 7, l = (i >> 3) & 63, ks = (i >> 9) & 1;
      int r10 = i >> 10;
      int tap = r10 % 9, chh = r10 / 9;
      int ol = l & 31, hh = l >> 5;
      int cl = ks*16 + hh*8 + e;            // channel within 32-block
      int c64 = chh*32 + cl;                // channel within 64-slab
      int ch8 = ch64*2 + chh;
      dst[(size_t)((((ch8*9 + tap)*2 + ks)*2 + o2)*512) + l*8 + e]
          = smb[ol*576 + c64*9 + tap];
    }
  } else if (b < 74){
    // 1x1 fragment packing (CW=32), one conv per block (16384 elems)
    int u = b - 64;
    for (int it = 0; it < 8; ++it){
      int i = tid + it*256;                 // [ch8][ks2][o2][l64][e8]
      int e = i & 7, l = (i >> 3) & 63, o2 = (i >> 9) & 1;
      int ks = (i >> 10) & 1, ch = i >> 11;
      int ol = l & 31, hh = l >> 5;
      int o = o2*32 + ol;
      int c = ch*32 + ks*16 + hh*8 + e;
      __bf16 v;
      if (u < 6){
        const float* w = (u < 3) ? (wa + (size_t)u*16384) : (wb + (size_t)(u-3)*16384);
        v = (__bf16)w[(size_t)o*256 + c];
      } else {
        int i9 = ((u == 6) || (u == 8)) ? 0 : 2;
        const float* w = ((u < 8) ? wST11 : wST12) + (size_t)i9*147456;
        v = (__bf16)w[((size_t)o*256 + c)*9 + 4];   // center tap
      }
      __bf16* dst = (u < 6) ? (wabp + (size_t)u*16384) : (wScp + (size_t)(u-6)*16384);
      dst[i] = v;
    }
  } else if (b < 842){
    int i = (b-74)*256 + tid;
    if (i < 196608) wdb[i] = (__bf16)wd[i];
  } else if (b == 842){
    int t = tid;
    if (t < 75){
      int s = t / 25, w = t % 25;
      float a[25], m[25];
      float mx = -3.4e38f;
      for (int v = 0; v < 25; ++v){
        float av = A[(s*25 + v)*25 + w];
        a[v] = av;
        float d = (v == w) ? 1.f : 0.f;
        float mm = (8.f*av*av*av*av - 4.f*av*av - 4.f*av + d) * 0.04f;
        m[v] = mm;
        mx = fmaxf(mx, mm);
      }
      float sum = 0.f;
      for (int v = 0; v < 25; ++v){ float e = __expf(m[v]-mx); m[v] = e; sum += e; }
      float inv = 1.f/sum;
      for (int v = 0; v < 25; ++v){
        float av = a[v];
        float d = (v == w) ? 1.f : 0.f;
        Aall[(s*25+v)*25 + w] = m[v]*inv + 4.f*av*av - av - 2.f*d + PA[(s*25+v)*25+w];
      }
    } else if (t >= 128){
      zp[t-128] = (__bf16)0.f;              // 128 x 2B = 256 B zero page
    }
  } else {
    int idx = b - 843;
    int p0 = (idx % 25)*64, c0 = ((idx/25) & 3)*64, n = idx/100;
    for (int i = tid; i < 4096; i += 256){
      int cc = i >> 6, pp = i & 63;
      smf[cc*65+pp] = x[(size_t)n*CTV + (size_t)(c0+cc)*TV + p0 + pp];
    }
    __syncthreads();
    for (int i = tid; i < 4096; i += 256){
      int pp = i >> 6, cc = i & 63;
      xt[((size_t)n*TV + p0+pp)*256 + c0+cc] = (__bf16)smf[cc*65+pp];
    }
  }
}

// ---------- MFMA conv v16: conv15 + bijective XCD swizzle (T1/m204) + prbase
// so phase-2 can be launched as two half-dispatches (visibility: lets the
// second-tier kernels surface in the rocprof top-5).
// Requires total grid count % 8 == 0 (560 / 224 / 224: all OK).
template<int NTAPS, int MINW>
__global__ __launch_bounds__(512, MINW) void conv16_k(const __bf16* __restrict__ xt,
    ConvPairs cp, const __bf16* __restrict__ zp, __bf16* __restrict__ fbuf,
    int prbase){
  extern __shared__ __bf16 sm[];
  constexpr int HALO  = (NTAPS==9) ? 100 : 0;
  constexpr int NROWS = 256 + 2*HALO;
  constexpr int SLOTS = NROWS*4;            // 16B slots per x buffer
  constexpr int KSTG  = (SLOTS + 511)/512;
  constexpr int NSTEP = NTAPS*2;            // KS=2 per 32-ch slice
  constexpr int AELE  = NTAPS*2*2*512;      // weight elems per conv per slice
  constexpr int ASLT  = 2*AELE/8;           // 16B slots, both convs
  constexpr int DEP   = (NSTEP >= 3) ? 3 : 2;
  // XCD-chunked bijective remap of the flattened workgroup id
  int nx = gridDim.x, ny = gridDim.y;
  int nwg = nx*ny*gridDim.z;
  int hw = blockIdx.x + nx*(blockIdx.y + ny*blockIdx.z);
  int q = nwg >> 3;
  int wg = (hw & 7)*q + (hw >> 3);
  int bx = wg % nx; int rem = wg / nx;
  int n  = rem % ny;
  int pr = prbase + rem / ny;
  int p0 = bx*256;
  int tid = threadIdx.x;
  int lane = tid & 63;
  int wave = tid >> 6;
  int which = wave >> 2, wq = wave & 3;
  int h = lane >> 5, l31 = lane & 31;
  const __bf16* xtn = xt + (size_t)n*CTV;
  const __bf16* wg0 = cp.wA[pr];
  const __bf16* wg1 = cp.wB[pr];
  __bf16* xb0 = sm;
  __bf16* xb1 = sm + NROWS*32;
  __bf16* Ab  = sm + 2*NROWS*32;

  f32x16 acc[2][2];   // [o2][pq]
  #pragma unroll
  for (int a=0;a<2;++a)
    #pragma unroll
    for (int b=0;b<2;++b)
      #pragma unroll
      for (int r=0;r<16;++r) acc[a][b][r] = 0.f;

  int rowbase = wq*64 + l31;

  auto stageX = [&](__bf16* bn, int ch){
    #pragma unroll
    for (int k=0; k<KSTG; ++k){
      int slot = k*512 + tid;
      if ((SLOTS & 511) && slot >= SLOTS) continue;
      const __bf16* src;
      if (NTAPS == 1){
        // fragment-linear: slot = ((pblk*2+ks)*2+h)*32 + l31s
        int l31s = slot & 31, f = slot >> 5;
        int h_ = f & 1, ks_ = (f >> 1) & 1, pblk = f >> 2;
        int pg = p0 + pblk*32 + l31s;
        src = (pg < 1600) ? (xtn + (size_t)pg*256 + ch*32 + ks_*16 + h_*8)
                          : zp;
      } else {
        int row = slot >> 2, g2 = slot & 3;
        int g = (g2 - (row>>1)) & 3;        // inverse of 8-bank-period swizzle
        int pg = p0 - HALO + row;
        src = ((unsigned)pg < 1600u) ? (xtn + (size_t)pg*256 + ch*32 + g*8)
                                     : zp;
      }
      gl_lds16(src, bn + (size_t)slot*8);
    }
  };
  auto stageA = [&](int ch){
    #pragma unroll
    for (int k=0; k<(ASLT+511)/512; ++k){
      int slot = k*512 + tid;
      if ((ASLT & 511) && slot >= ASLT) continue;
      int cv = (slot >= AELE/8) ? 1 : 0;
      int off = (slot - cv*(AELE/8))*8;
      const __bf16* src = (cv ? wg1 : wg0) + (size_t)ch*AELE + off;
      gl_lds16(src, Ab + cv*AELE + off);
    }
  };
  const __bf16* aw = Ab + which*AELE + lane*8;
  auto ldA = [&](int s, v8bf* aa){
    int off = s*1024;                       // (tap*2+ks)*2*512
    aa[0] = *(const v8bf*)(aw + off);
    aa[1] = *(const v8bf*)(aw + off + 512);
  };
  auto ldB = [&](const __bf16* bc, int s, v8bf* bb){
    int tap = s >> 1, ks = s & 1;
    #pragma unroll
    for (int pq=0; pq<2; ++pq){
      if (NTAPS == 1){
        int frag = ((wq*2 + pq)*2 + ks)*2 + h;
        bb[pq] = *(const v8bf*)(bc + frag*256 + l31*8);  // contiguous wave read
      } else {
        int row = tap*25 + rowbase + pq*32;
        int gs = ((ks*2 + h) + (row>>1)) & 3;            // 8-bank-period swizzle
        bb[pq] = *(const v8bf*)(bc + row*32 + gs*8);
      }
    }
  };

  stageA(0);
  stageX(xb0, 0);
  __syncthreads();

  v8bf ar[DEP][2], bR[DEP][2];
  for (int ch=0; ch<8; ++ch){
    const __bf16* bc = (ch & 1) ? xb1 : xb0;
    __bf16*       bn = (ch & 1) ? xb0 : xb1;
    if (ch < 7) stageX(bn, ch+1);           // lands under the MFMA loop
    #pragma unroll
    for (int i=0; i<DEP; ++i){
      if (i < NSTEP){ ldA(i, ar[i]); ldB(bc, i, bR[i]); }
    }
    #pragma unroll
    for (int s=0; s<NSTEP; ++s){
      int c = s % DEP;
      v8bf A0 = ar[c][0], A1 = ar[c][1];
      v8bf B0 = bR[c][0], B1 = bR[c][1];
      if (s+DEP < NSTEP){
        ldB(bc, s+DEP, bR[c]);
        ldA(s+DEP, ar[c]);
      }
      __builtin_amdgcn_s_setprio(1);
      acc[0][0] = __builtin_amdgcn_mfma_f32_32x32x16_bf16(A0, B0, acc[0][0], 0,0,0);
      acc[1][0] = __builtin_amdgcn_mfma_f32_32x32x16_bf16(A1, B0, acc[1][0], 0,0,0);
      acc[0][1] = __builtin_amdgcn_mfma_f32_32x32x16_bf16(A0, B1, acc[0][1], 0,0,0);
      acc[1][1] = __builtin_amdgcn_mfma_f32_32x32x16_bf16(A1, B1, acc[1][1], 0,0,0);
      __builtin_amdgcn_s_setprio(0);
    }
    __syncthreads();                        // all reads of Ab/xb done; x-stage drained
    if (ch < 7) stageA(ch+1);               // overwrite Ab for next slice
    __syncthreads();                        // A writes visible
  }

  const float* bias = which ? cp.bB[pr] : cp.bA[pr];
  __bf16* outb = fbuf + (size_t)(pr*2 + which)*NICTV + (size_t)n*TV*64;
  #pragma unroll
  for (int pq=0; pq<2; ++pq){
    int p = p0 + wq*64 + pq*32 + l31;
    if (p >= 1600) continue;
    __bf16* orow = outb + (size_t)p*64;
    #pragma unroll
    for (int of=0; of<2; ++of){
      #pragma unroll
      for (int g=0; g<4; ++g){
        int og = of*32 + 8*g + 4*h;
        v4bf pk;
        #pragma unroll
        for (int j=0;j<4;++j) pk[j] = (__bf16)(acc[of][pq][4*g+j] + bias[og+j]);
        *(v4bf*)(orow + og) = pk;
      }
    }
  }
}

// ---------- u GEMM v6: br-merged — stage x-tile once, sweep 3 branches.
// grid (25 ptile64, 16 n), block 256 (4 waves = o-slices of 64), LDS 32 KB.
__global__ __launch_bounds__(256, 2) void ugemm6_k(const __bf16* __restrict__ xt,
    const __bf16* __restrict__ wdb, __bf16* __restrict__ ubuf){
  __shared__ __bf16 sm[64*256];
  int p0 = blockIdx.x*64;
  int n  = blockIdx.y;
  int tid = threadIdx.x;
  int lane = tid & 63;
  int os = tid >> 6;
  int h = lane >> 5, l31 = lane & 31;
  const __bf16* xtn = xt + (size_t)n*CTV;

  for (int s2 = tid; s2 < 64*32; s2 += 256){
    int row = s2 >> 5, g = s2 & 31;
    uint4 val = *(const uint4*)(xtn + (size_t)(p0+row)*256 + g*8);
    int gs = (g + row) & 31;
    *(uint4*)(sm + row*256 + gs*8) = val;
  }
  __syncthreads();

  auto ldB = [&](int ks, v8bf* bb){
    #pragma unroll
    for (int pq=0; pq<2; ++pq){
      int row = pq*32 + l31;
      int gs = ((ks*2 + h) + row) & 31;
      bb[pq] = *(const v8bf*)(sm + row*256 + gs*8);
    }
  };

  for (int br=0; br<3; ++br){
    const __bf16* wl = wdb + ((size_t)br*256 + os*64 + l31)*256 + h*8;
    auto ldA = [&](int ks, v8bf& A0, v8bf& A1){
      A0 = *(const v8bf*)(wl + ks*16);
      A1 = *(const v8bf*)(wl + (size_t)32*256 + ks*16);
    };
    f32x16 acc[2][2];
    #pragma unroll
    for (int a=0;a<2;++a)
      #pragma unroll
      for (int b=0;b<2;++b)
        #pragma unroll
        for (int r=0;r<16;++r) acc[a][b][r] = 0.f;

    v8bf a0[4], a1[4];
    ldA(0, a0[0], a1[0]);
    ldA(1, a0[1], a1[1]);
    ldA(2, a0[2], a1[2]);
    ldA(3, a0[3], a1[3]);
    v8bf bR[2][2];
    ldB(0, bR[0]);
    ldB(1, bR[1]);
    #pragma unroll
    for (int ks=0; ks<16; ++ks){
      int c2 = ks & 1, cur = ks & 3;
      v8bf B0 = bR[c2][0], B1 = bR[c2][1];
      v8bf A0 = a0[cur], A1 = a1[cur];
      if (ks+2 < 16) ldB(ks+2, bR[c2]);
      if (ks+4 < 16) ldA(ks+4, a0[cur], a1[cur]);
      acc[0][0] = __builtin_amdgcn_mfma_f32_32x32x16_bf16(A0, B0, acc[0][0], 0,0,0);
      acc[1][0] = __builtin_amdgcn_mfma_f32_32x32x16_bf16(A1, B0, acc[1][0], 0,0,0);
      acc[0][1] = __builtin_amdgcn_mfma_f32_32x32x16_bf16(A0, B1, acc[0][1], 0,0,0);
      acc[1][1] = __builtin_amdgcn_mfma_f32_32x32x16_bf16(A1, B1, acc[1][1], 0,0,0);
    }

    #pragma unroll
    for (int pq=0; pq<2; ++pq){
      int p = p0 + pq*32 + l31;
      __bf16* out = ubuf + ((size_t)(br*NN + n)*TV + p)*256;
      #pragma unroll
      for (int oq=0; oq<2; ++oq){
        #pragma unroll
        for (int g=0; g<4; ++g){
          int og = os*64 + oq*32 + 8*g + 4*h;
          v4bf pk;
          #pragma unroll
          for (int j=0;j<4;++j) pk[j] = (__bf16)acc[oq][pq][4*g+j];
          *(v4bf*)(out + og) = pk;
        }
      }
    }
  }
}

// ---------- scores v2: MFMA + in-block chunk reduce -> 4KB coalesced partial.
__global__ __launch_bounds__(256) void scores_m2_k(const __bf16* __restrict__ fbuf,
                                                   float* __restrict__ part, int pairbase){
  __shared__ float smp[4][1024];
  int bx = blockIdx.x, n = blockIdx.y, pr = blockIdx.z;
  int tid = threadIdx.x;
  int lane = tid & 63;
  int wave = tid >> 6;
  int chunk = bx*4 + wave;
  int h = lane >> 5, l31 = lane & 31;
  const __bf16* f1 = fbuf + (size_t)(pr*2)*NICTV   + (size_t)n*TV*64;
  const __bf16* f2 = fbuf + (size_t)(pr*2+1)*NICTV + (size_t)n*TV*64;
  int t0 = chunk*4;

  f32x16 acc;
  #pragma unroll
  for (int r=0;r<16;++r) acc[r] = 0.f;

  auto off = [&](int s)->size_t{
    int t = t0 + (s>>2), og = s&3;
    return ((size_t)(t*25 + l31))*64 + og*16 + h*8;
  };
  v8bf A[4], B[4];
  #pragma unroll
  for (int i=0; i<4; ++i){
    size_t o = off(i);
    A[i] = *(const v8bf*)(f1+o); B[i] = *(const v8bf*)(f2+o);
  }
  #pragma unroll
  for (int s=0; s<16; ++s){
    int cur = s & 3;
    v8bf Ac = A[cur], Bc = B[cur];
    if (s+4 < 16){
      size_t o2 = off(s+4);
      A[cur] = *(const v8bf*)(f1+o2);
      B[cur] = *(const v8bf*)(f2+o2);
    }
    acc = __builtin_amdgcn_mfma_f32_32x32x16_bf16(Ac, Bc, acc, 0,0,0);
  }

  #pragma unroll
  for (int r=0; r<16; ++r){
    int row = (r&3) + 8*(r>>2) + 4*h;
    smp[wave][row*32 + l31] = acc[r];
  }
  __syncthreads();
  for (int j = tid; j < 1024; j += 256){
    float s = smp[0][j] + smp[1][j] + smp[2][j] + smp[3][j];
    part[(((size_t)(pairbase+pr)*NN + n)*4 + bx)*1024 + j] = s;
  }
}

// ---------- finalize v2: one thread per (v,w) cell; LDS tree softmax.
// grid (16,3), block (32w x 25v) = 800 thr. Per-thread state = 1 float.
__global__ __launch_bounds__(800) void finalize2_k(const float* __restrict__ part,
    const float* __restrict__ Aall, float* __restrict__ Ai3){
  __shared__ float smR[25][33];
  int n = blockIdx.x, br = blockIdx.y;
  int w = threadIdx.x;                      // 0..31 (w<25 active for I/O)
  int v = threadIdx.y;                      // 0..24
  const int prs0[3] = {0,3,5}, prs1[3] = {1,6,8}, prs2[3] = {2,4,7};
  const int* prs = (br==0) ? prs0 : (br==1) ? prs1 : prs2;
  float acc = 0.f;
  for (int k=0; k<3; ++k){
    const float* pb = part + ((size_t)prs[k]*NN + n)*4096;
    float s = 0.f;
    if (w < 25){
      s = pb[v*32+w] + pb[1024+v*32+w] + pb[2048+v*32+w] + pb[3072+v*32+w];
      s *= (1.f/4096.f);
    }
    smR[v][w] = s;
    __syncthreads();
    #pragma unroll
    for (int d=16; d>0; d>>=1){
      if (v < d){
        float o = (v+d < 25) ? smR[v+d][w] : -3.4e38f;
        smR[v][w] = fmaxf(smR[v][w], o);
      }
      __syncthreads();
    }
    float mx = smR[0][w];
    __syncthreads();
    float e = __expf(s - mx);
    smR[v][w] = e;
    __syncthreads();
    #pragma unroll
    for (int d=16; d>0; d>>=1){
      if (v < d){
        float o = (v+d < 25) ? smR[v+d][w] : 0.f;
        smR[v][w] += o;
      }
      __syncthreads();
    }
    float sum = smR[0][w];
    __syncthreads();
    acc += e / sum;
  }
  if (w < 25)
    Ai3[((size_t)br*NN + n)*625 + v*25 + w] =
      Aall[br*625 + v*25 + w] + acc;
}

// ---------- epilogue v2: y + BN + residual + relu, coalesced I/O via LDS
__global__ __launch_bounds__(256) void yep_k(const float* __restrict__ x,
    const float* __restrict__ Ai3, const __bf16* __restrict__ ubuf,
    const float* __restrict__ bd, const float* __restrict__ gamma,
    const float* __restrict__ beta, const float* __restrict__ bnm,
    const float* __restrict__ bnv, float* __restrict__ out){
  __shared__ float ais[3][25*28];
  __shared__ float xs[6400];                // 256 o x 25 w staging
  int t = blockIdx.x, n = blockIdx.y, o = threadIdx.x;
  for (int l=o; l<2100; l+=256){
    int br = l/700, r = l%700;
    int v = r/28, w = r%28;
    ais[br][v*28+w] = (w<25) ? Ai3[((size_t)br*NN + n)*625 + v*25 + w] : 0.f;
  }
  // coalesced x-read: linear (o*25+w) mapping -> 100B runs
  for (int li=o; li<6400; li+=256){
    int oo = li/25, ww = li%25;
    xs[li] = x[(size_t)n*CTV + (size_t)oo*TV + t*25 + ww];
  }
  __syncthreads();
  float y[28];
  #pragma unroll
  for (int w=0;w<28;++w) y[w]=0.f;
  for (int br=0; br<3; ++br){
    const __bf16* up = ubuf + ((size_t)(br*NN + n)*TV + t*25)*256 + o;
    float uv[25];
    #pragma unroll
    for (int v=0;v<25;++v) uv[v] = (float)up[(size_t)v*256];
    const float* ab = ais[br];
    for (int v=0; v<25; ++v){
      float u = uv[v];
      #pragma unroll
      for (int j=0; j<7; ++j){
        float4 a4 = *(const float4*)(ab + v*28 + 4*j);
        y[4*j+0] = fmaf(u, a4.x, y[4*j+0]);
        y[4*j+1] = fmaf(u, a4.y, y[4*j+1]);
        y[4*j+2] = fmaf(u, a4.z, y[4*j+2]);
        y[4*j+3] = fmaf(u, a4.w, y[4*j+3]);
      }
    }
  }
  float bsum = bd[o] + bd[256+o] + bd[512+o];
  float sc = gamma[o] * rsqrtf(bnv[o] + 1e-5f);
  float m  = bnm[o], be = beta[o];
  #pragma unroll
  for (int w=0; w<25; ++w)
    xs[o*25+w] = fmaxf((y[w] + bsum - m)*sc + be + xs[o*25+w], 0.f);
  __syncthreads();
  // coalesced write-out
  for (int li=o; li<6400; li+=256){
    int oo = li/25, ww = li%25;
    out[(size_t)n*CTV + (size_t)oo*TV + t*25 + ww] = xs[li];
  }
}

extern "C" void kernel_launch(void* const* d_in, const int* in_sizes, int n_in,
                              void* d_out, int out_size, void* d_ws, size_t ws_size,
                              hipStream_t stream) {
  const float* x     = (const float*)d_in[0];
  const float* A     = (const float*)d_in[1];
  const float* PA    = (const float*)d_in[2];
  const float* wa    = (const float*)d_in[3];
  const float* ba    = (const float*)d_in[4];
  const float* wb    = (const float*)d_in[5];
  const float* bb    = (const float*)d_in[6];
  const float* wT1   = (const float*)d_in[7];
  const float* bT1   = (const float*)d_in[8];
  const float* wT2   = (const float*)d_in[9];
  const float* bT2   = (const float*)d_in[10];
  const float* wST11 = (const float*)d_in[11];
  const float* bST11 = (const float*)d_in[12];
  const float* wST12 = (const float*)d_in[13];
  const float* bST12 = (const float*)d_in[14];
  const float* wd    = (const float*)d_in[15];
  const float* bd    = (const float*)d_in[16];
  const float* gamma = (const float*)d_in[17];
  const float* beta  = (const float*)d_in[18];
  const float* bnm   = (const float*)d_in[19];
  const float* bnv   = (const float*)d_in[20];

  char* W = (char*)d_ws;
  float*  Aall = (float*)W;  W += 8192;
  __bf16* zp   = (__bf16*)W; W += 256;       // zero page for OOB staging
  float*  Ai3  = (float*)W;  W += 122880;
  __bf16* wabp = (__bf16*)W; W += 196608;    // 6 packed 1x1 convs (wa x3, wb x3)
  __bf16* wScp = (__bf16*)W; W += 131072;    // 4 packed center-tap convs
  __bf16* wT1p = (__bf16*)W; W += 884736;    // 3 packed 9-tap convs
  __bf16* wT2p = (__bf16*)W; W += 884736;
  __bf16* wS1p = (__bf16*)W; W += 294912;    // s=1 only
  __bf16* wS2p = (__bf16*)W; W += 294912;
  __bf16* wdb  = (__bf16*)W; W += 393216;
  __bf16* xt   = (__bf16*)W; W += 13107200;
  char* R = W;               W += 39321600;  // fbuf (10 slices) / ubuf overlay
  float*  part = (float*)W;  W += 2359296;   // 9*16*4*1024 f32 (chunk-reduced)
  __bf16* fbuf = (__bf16*)R;
  __bf16* ubuf = (__bf16*)R;

  // merged prep
  prep_k<<<2443, 256, 0, stream>>>(x, xt, wT1, wT2, wST11, wST12,
                                   wT1p, wT2p, wS1p, wS2p,
                                   wa, wb, wabp, wScp, wd, wdb, A, PA, Aall, zp);

  // phase 1: all "1x1" pairs (A x3, ST-even x2 via packed center-tap) -> pairs 0..4
  {
    ConvPairs cp;
    for (int i=0;i<3;++i){
      cp.wA[i] = wabp + (size_t)i*16384;      cp.wB[i] = wabp + (size_t)(3+i)*16384;
      cp.bA[i] = ba + i*64;                   cp.bB[i] = bb + i*64;
    }
    int evens[2] = {0, 2};
    for (int j=0;j<2;++j){
      int i = evens[j];
      cp.wA[3+j] = wScp + (size_t)j*16384;    cp.wB[3+j] = wScp + (size_t)(2+j)*16384;
      cp.bA[3+j] = bST11 + i*64;              cp.bB[3+j] = bST12 + i*64;
    }
    // LDS: 2 x-bufs (256*32) + A (2*2048) = 20480 elems = 40960 B; 560 blocks %8==0
    conv16_k<1,4><<<dim3(7,16,5), 512, 40960, stream>>>(xt, cp, zp, fbuf, 0);
    scores_m2_k<<<dim3(4,16,5), 256, 0, stream>>>(fbuf, part, 0);
  }

  // phase 2: all 9-tap pairs (T x3, ST-odd x1) -> pairs 5..8, as TWO half
  // dispatches (pairs 0-1 / 2-3) so second-tier kernels surface in top-5.
  {
    ConvPairs cp;
    for (int i=0;i<3;++i){
      cp.wA[i] = wT1p + (size_t)i*147456;  cp.wB[i] = wT2p + (size_t)i*147456;
      cp.bA[i] = bT1 + i*64;               cp.bB[i] = bT2 + i*64;
    }
    cp.wA[3] = wS1p;  cp.wB[3] = wS2p;
    cp.bA[3] = bST11 + 64;  cp.bB[3] = bST12 + 64;
    cp.wA[4] = cp.wA[3]; cp.wB[4] = cp.wB[3]; cp.bA[4] = cp.bA[3]; cp.bB[4] = cp.bB[3];
    // LDS: 2 x-bufs (456*32) + A (2*18432) = 66048 elems = 132096 B; 224 blocks each
    conv16_k<9,2><<<dim3(7,16,2), 512, 132096, stream>>>(xt, cp, zp, fbuf, 0);
    conv16_k<9,2><<<dim3(7,16,2), 512, 132096, stream>>>(xt, cp, zp, fbuf, 2);
    scores_m2_k<<<dim3(4,16,4), 256, 0, stream>>>(fbuf, part, 5);
  }

  // u GEMM (overwrites fbuf region — dead after phase-2 scores)
  ugemm6_k<<<dim3(25,16), 256, 0, stream>>>(xt, wdb, ubuf);
  // all-pair softmax -> Ai3 (one thread per (v,w); no scratch arrays)
  finalize2_k<<<dim3(16,3), dim3(32,25), 0, stream>>>(part, Aall, Ai3);
  // epilogue
  yep_k<<<dim3(64,16), 256, 0, stream>>>(x, Ai3, ubuf, bd, gamma, beta, bnm, bnv,
                                         (float*)d_out);
}

// Round 12
// 322.143 us; speedup vs baseline: 1.0628x; 1.0628x over previous
//
#include <hip/hip_runtime.h>
#include <hip/hip_bf16.h>

#define NN 16
#define CC 256
#define TT 64
#define VV 25
#define ICC 64
#define TV 1600      // TT*VV
#define CTV 409600   // CC*TV
#define NICTV 1638400  // elements per f-slice: 16*1600*64

typedef __bf16 v8bf __attribute__((ext_vector_type(8)));
typedef __bf16 v4bf __attribute__((ext_vector_type(4)));
typedef float f32x16 __attribute__((ext_vector_type(16)));

struct ConvPairs {
  const __bf16* wA[5];
  const __bf16* wB[5];
  const float*  bA[5];
  const float*  bB[5];
};

__device__ __forceinline__ void gl_lds16(const __bf16* g, __bf16* l){
  __builtin_amdgcn_global_load_lds(
      (const __attribute__((address_space(1))) unsigned int*)g,
      (__attribute__((address_space(3))) unsigned int*)l, 16, 0, 0);
}

// ---------- merged prep: sections by blockIdx.x
// [0,64)     pack 9-tap weights fragment-linear (CW=32):
//            per conv layout: [(ch8*9+tap)*2+ks][o2][lane64][e8] bf16
// [64,74)    pack 1x1 weights (CW=32): [(ch8*2+ks)][o2][lane64][e8]
// [74,842)   wd -> bf16
// [842]      a_all + zero-page
// [843,2443) xt: x -> channels-last bf16
__global__ __launch_bounds__(256) void prep_k(
    const float* __restrict__ x, __bf16* __restrict__ xt,
    const float* __restrict__ wT1, const float* __restrict__ wT2,
    const float* __restrict__ wST11, const float* __restrict__ wST12,
    __bf16* __restrict__ wT1p, __bf16* __restrict__ wT2p,
    __bf16* __restrict__ wS1p, __bf16* __restrict__ wS2p,
    const float* __restrict__ wa, const float* __restrict__ wb,
    __bf16* __restrict__ wabp, __bf16* __restrict__ wScp,
    const float* __restrict__ wd, __bf16* __restrict__ wdb,
    const float* __restrict__ A, const float* __restrict__ PA,
    float* __restrict__ Aall, __bf16* __restrict__ zp){
  __shared__ __align__(16) float smf[64*65];
  __bf16* smb = (__bf16*)smf;
  int b = blockIdx.x;
  int tid = threadIdx.x;
  if (b < 64){
    // 9-tap fragment packing. t: 0-2 wT1 s, 3-5 wT2 s, 6 wST11 s=1, 7 wST12 s=1
    int t = b >> 3, ch64 = (b >> 1) & 3, o2 = b & 1;
    const float* src; __bf16* dst;
    if (t < 3)      { src = wT1  + (size_t)t*147456;     dst = wT1p + (size_t)t*147456; }
    else if (t < 6) { src = wT2  + (size_t)(t-3)*147456; dst = wT2p + (size_t)(t-3)*147456; }
    else if (t == 6){ src = wST11 + 147456;              dst = wS1p; }
    else            { src = wST12 + 147456;              dst = wS2p; }
    const float* in = src + (size_t)(o2*32)*2304 + ch64*576;
    // stage 32 o-rows x 576 f32 (64 ch x 9 taps) as bf16
    for (int i = tid; i < 32*576; i += 256){
      int row = i / 576, cc = i % 576;
      smb[i] = (__bf16)in[(size_t)row*2304 + cc];
    }
    __syncthreads();
    // emit: chhalf(2) x tap(9) x ks(2) x lane(64) x e(8) = 18432
    for (int i = tid; i < 18432; i += 256){
      int e = i & 7, l = (i >> 3) & 63, ks = (i >> 9) & 1;
      int r10 = i >> 10;
      int tap = r10 % 9, chh = r10 / 9;
      int ol = l & 31, hh = l >> 5;
      int cl = ks*16 + hh*8 + e;            // channel within 32-block
      int c64 = chh*32 + cl;                // channel within 64-slab
      int ch8 = ch64*2 + chh;
      dst[(size_t)((((ch8*9 + tap)*2 + ks)*2 + o2)*512) + l*8 + e]
          = smb[ol*576 + c64*9 + tap];
    }
  } else if (b < 74){
    // 1x1 fragment packing (CW=32), one conv per block (16384 elems)
    int u = b - 64;
    for (int it = 0; it < 8; ++it){
      int i = tid + it*256;                 // [ch8][ks2][o2][l64][e8]
      int e = i & 7, l = (i >> 3) & 63, o2 = (i >> 9) & 1;
      int ks = (i >> 10) & 1, ch = i >> 11;
      int ol = l & 31, hh = l >> 5;
      int o = o2*32 + ol;
      int c = ch*32 + ks*16 + hh*8 + e;
      __bf16 v;
      if (u < 6){
        const float* w = (u < 3) ? (wa + (size_t)u*16384) : (wb + (size_t)(u-3)*16384);
        v = (__bf16)w[(size_t)o*256 + c];
      } else {
        int i9 = ((u == 6) || (u == 8)) ? 0 : 2;
        const float* w = ((u < 8) ? wST11 : wST12) + (size_t)i9*147456;
        v = (__bf16)w[((size_t)o*256 + c)*9 + 4];   // center tap
      }
      __bf16* dst = (u < 6) ? (wabp + (size_t)u*16384) : (wScp + (size_t)(u-6)*16384);
      dst[i] = v;
    }
  } else if (b < 842){
    int i = (b-74)*256 + tid;
    if (i < 196608) wdb[i] = (__bf16)wd[i];
  } else if (b == 842){
    int t = tid;
    if (t < 75){
      int s = t / 25, w = t % 25;
      float a[25], m[25];
      float mx = -3.4e38f;
      for (int v = 0; v < 25; ++v){
        float av = A[(s*25 + v)*25 + w];
        a[v] = av;
        float d = (v == w) ? 1.f : 0.f;
        float mm = (8.f*av*av*av*av - 4.f*av*av - 4.f*av + d) * 0.04f;
        m[v] = mm;
        mx = fmaxf(mx, mm);
      }
      float sum = 0.f;
      for (int v = 0; v < 25; ++v){ float e = __expf(m[v]-mx); m[v] = e; sum += e; }
      float inv = 1.f/sum;
      for (int v = 0; v < 25; ++v){
        float av = a[v];
        float d = (v == w) ? 1.f : 0.f;
        Aall[(s*25+v)*25 + w] = m[v]*inv + 4.f*av*av - av - 2.f*d + PA[(s*25+v)*25+w];
      }
    } else if (t >= 128){
      zp[t-128] = (__bf16)0.f;              // 128 x 2B = 256 B zero page
    }
  } else {
    int idx = b - 843;
    int p0 = (idx % 25)*64, c0 = ((idx/25) & 3)*64, n = idx/100;
    for (int i = tid; i < 4096; i += 256){
      int cc = i >> 6, pp = i & 63;
      smf[cc*65+pp] = x[(size_t)n*CTV + (size_t)(c0+cc)*TV + p0 + pp];
    }
    __syncthreads();
    for (int i = tid; i < 4096; i += 256){
      int pp = i >> 6, cc = i & 63;
      xt[((size_t)n*TV + p0+pp)*256 + c0+cc] = (__bf16)smf[cc*65+pp];
    }
  }
}

// ---------- MFMA conv v15 (r10 config, reverted verbatim): weights via LDS.
// 9-tap LDS 132KB -> 1 block/CU (MINW=2); 1x1 LDS 41KB -> 2 blocks (MINW=4).
template<int NTAPS, int MINW>
__global__ __launch_bounds__(512, MINW) void conv15_k(const __bf16* __restrict__ xt,
    ConvPairs cp, const __bf16* __restrict__ zp, __bf16* __restrict__ fbuf){
  extern __shared__ __bf16 sm[];
  constexpr int HALO  = (NTAPS==9) ? 100 : 0;
  constexpr int NROWS = 256 + 2*HALO;
  constexpr int SLOTS = NROWS*4;            // 16B slots per x buffer
  constexpr int KSTG  = (SLOTS + 511)/512;
  constexpr int NSTEP = NTAPS*2;            // KS=2 per 32-ch slice
  constexpr int AELE  = NTAPS*2*2*512;      // weight elems per conv per slice
  constexpr int ASLT  = 2*AELE/8;           // 16B slots, both convs
  constexpr int DEP   = (NSTEP >= 3) ? 3 : 2;
  int p0 = blockIdx.x*256;
  int n  = blockIdx.y;
  int pr = blockIdx.z;
  int tid = threadIdx.x;
  int lane = tid & 63;
  int wave = tid >> 6;
  int which = wave >> 2, wq = wave & 3;
  int h = lane >> 5, l31 = lane & 31;
  const __bf16* xtn = xt + (size_t)n*CTV;
  const __bf16* wg0 = cp.wA[pr];
  const __bf16* wg1 = cp.wB[pr];
  __bf16* xb0 = sm;
  __bf16* xb1 = sm + NROWS*32;
  __bf16* Ab  = sm + 2*NROWS*32;

  f32x16 acc[2][2];   // [o2][pq]
  #pragma unroll
  for (int a=0;a<2;++a)
    #pragma unroll
    for (int b=0;b<2;++b)
      #pragma unroll
      for (int r=0;r<16;++r) acc[a][b][r] = 0.f;

  int rowbase = wq*64 + l31;

  auto stageX = [&](__bf16* bn, int ch){
    #pragma unroll
    for (int k=0; k<KSTG; ++k){
      int slot = k*512 + tid;
      if ((SLOTS & 511) && slot >= SLOTS) continue;
      const __bf16* src;
      if (NTAPS == 1){
        // fragment-linear: slot = ((pblk*2+ks)*2+h)*32 + l31s
        int l31s = slot & 31, f = slot >> 5;
        int h_ = f & 1, ks_ = (f >> 1) & 1, pblk = f >> 2;
        int pg = p0 + pblk*32 + l31s;
        src = (pg < 1600) ? (xtn + (size_t)pg*256 + ch*32 + ks_*16 + h_*8)
                          : zp;
      } else {
        int row = slot >> 2, g2 = slot & 3;
        int g = (g2 - (row>>1)) & 3;        // inverse of 8-bank-period swizzle
        int pg = p0 - HALO + row;
        src = ((unsigned)pg < 1600u) ? (xtn + (size_t)pg*256 + ch*32 + g*8)
                                     : zp;
      }
      gl_lds16(src, bn + (size_t)slot*8);
    }
  };
  auto stageA = [&](int ch){
    #pragma unroll
    for (int k=0; k<(ASLT+511)/512; ++k){
      int slot = k*512 + tid;
      if ((ASLT & 511) && slot >= ASLT) continue;
      int cv = (slot >= AELE/8) ? 1 : 0;
      int off = (slot - cv*(AELE/8))*8;
      const __bf16* src = (cv ? wg1 : wg0) + (size_t)ch*AELE + off;
      gl_lds16(src, Ab + cv*AELE + off);
    }
  };
  const __bf16* aw = Ab + which*AELE + lane*8;
  auto ldA = [&](int s, v8bf* aa){
    int off = s*1024;                       // (tap*2+ks)*2*512
    aa[0] = *(const v8bf*)(aw + off);
    aa[1] = *(const v8bf*)(aw + off + 512);
  };
  auto ldB = [&](const __bf16* bc, int s, v8bf* bb){
    int tap = s >> 1, ks = s & 1;
    #pragma unroll
    for (int pq=0; pq<2; ++pq){
      if (NTAPS == 1){
        int frag = ((wq*2 + pq)*2 + ks)*2 + h;
        bb[pq] = *(const v8bf*)(bc + frag*256 + l31*8);  // contiguous wave read
      } else {
        int row = tap*25 + rowbase + pq*32;
        int gs = ((ks*2 + h) + (row>>1)) & 3;            // 8-bank-period swizzle
        bb[pq] = *(const v8bf*)(bc + row*32 + gs*8);
      }
    }
  };

  stageA(0);
  stageX(xb0, 0);
  __syncthreads();

  v8bf ar[DEP][2], bR[DEP][2];
  for (int ch=0; ch<8; ++ch){
    const __bf16* bc = (ch & 1) ? xb1 : xb0;
    __bf16*       bn = (ch & 1) ? xb0 : xb1;
    if (ch < 7) stageX(bn, ch+1);           // lands under the MFMA loop
    #pragma unroll
    for (int i=0; i<DEP; ++i){
      if (i < NSTEP){ ldA(i, ar[i]); ldB(bc, i, bR[i]); }
    }
    #pragma unroll
    for (int s=0; s<NSTEP; ++s){
      int c = s % DEP;
      v8bf A0 = ar[c][0], A1 = ar[c][1];
      v8bf B0 = bR[c][0], B1 = bR[c][1];
      if (s+DEP < NSTEP){
        ldB(bc, s+DEP, bR[c]);
        ldA(s+DEP, ar[c]);
      }
      __builtin_amdgcn_s_setprio(1);
      acc[0][0] = __builtin_amdgcn_mfma_f32_32x32x16_bf16(A0, B0, acc[0][0], 0,0,0);
      acc[1][0] = __builtin_amdgcn_mfma_f32_32x32x16_bf16(A1, B0, acc[1][0], 0,0,0);
      acc[0][1] = __builtin_amdgcn_mfma_f32_32x32x16_bf16(A0, B1, acc[0][1], 0,0,0);
      acc[1][1] = __builtin_amdgcn_mfma_f32_32x32x16_bf16(A1, B1, acc[1][1], 0,0,0);
      __builtin_amdgcn_s_setprio(0);
    }
    __syncthreads();                        // all reads of Ab/xb done; x-stage drained
    if (ch < 7) stageA(ch+1);               // overwrite Ab for next slice
    __syncthreads();                        // A writes visible
  }

  const float* bias = which ? cp.bB[pr] : cp.bA[pr];
  __bf16* outb = fbuf + (size_t)(pr*2 + which)*NICTV + (size_t)n*TV*64;
  #pragma unroll
  for (int pq=0; pq<2; ++pq){
    int p = p0 + wq*64 + pq*32 + l31;
    if (p >= 1600) continue;
    __bf16* orow = outb + (size_t)p*64;
    #pragma unroll
    for (int of=0; of<2; ++of){
      #pragma unroll
      for (int g=0; g<4; ++g){
        int og = of*32 + 8*g + 4*h;
        v4bf pk;
        #pragma unroll
        for (int j=0;j<4;++j) pk[j] = (__bf16)(acc[of][pq][4*g+j] + bias[og+j]);
        *(v4bf*)(orow + og) = pk;
      }
    }
  }
}

// ---------- u GEMM v6: br-merged — stage x-tile once, sweep 3 branches.
// grid (25 ptile64, 16 n), block 256 (4 waves = o-slices of 64), LDS 32 KB.
__global__ __launch_bounds__(256, 2) void ugemm6_k(const __bf16* __restrict__ xt,
    const __bf16* __restrict__ wdb, __bf16* __restrict__ ubuf){
  __shared__ __bf16 sm[64*256];
  int p0 = blockIdx.x*64;
  int n  = blockIdx.y;
  int tid = threadIdx.x;
  int lane = tid & 63;
  int os = tid >> 6;
  int h = lane >> 5, l31 = lane & 31;
  const __bf16* xtn = xt + (size_t)n*CTV;

  for (int s2 = tid; s2 < 64*32; s2 += 256){
    int row = s2 >> 5, g = s2 & 31;
    uint4 val = *(const uint4*)(xtn + (size_t)(p0+row)*256 + g*8);
    int gs = (g + row) & 31;
    *(uint4*)(sm + row*256 + gs*8) = val;
  }
  __syncthreads();

  auto ldB = [&](int ks, v8bf* bb){
    #pragma unroll
    for (int pq=0; pq<2; ++pq){
      int row = pq*32 + l31;
      int gs = ((ks*2 + h) + row) & 31;
      bb[pq] = *(const v8bf*)(sm + row*256 + gs*8);
    }
  };

  for (int br=0; br<3; ++br){
    const __bf16* wl = wdb + ((size_t)br*256 + os*64 + l31)*256 + h*8;
    auto ldA = [&](int ks, v8bf& A0, v8bf& A1){
      A0 = *(const v8bf*)(wl + ks*16);
      A1 = *(const v8bf*)(wl + (size_t)32*256 + ks*16);
    };
    f32x16 acc[2][2];
    #pragma unroll
    for (int a=0;a<2;++a)
      #pragma unroll
      for (int b=0;b<2;++b)
        #pragma unroll
        for (int r=0;r<16;++r) acc[a][b][r] = 0.f;

    v8bf a0[4], a1[4];
    ldA(0, a0[0], a1[0]);
    ldA(1, a0[1], a1[1]);
    ldA(2, a0[2], a1[2]);
    ldA(3, a0[3], a1[3]);
    v8bf bR[2][2];
    ldB(0, bR[0]);
    ldB(1, bR[1]);
    #pragma unroll
    for (int ks=0; ks<16; ++ks){
      int c2 = ks & 1, cur = ks & 3;
      v8bf B0 = bR[c2][0], B1 = bR[c2][1];
      v8bf A0 = a0[cur], A1 = a1[cur];
      if (ks+2 < 16) ldB(ks+2, bR[c2]);
      if (ks+4 < 16) ldA(ks+4, a0[cur], a1[cur]);
      acc[0][0] = __builtin_amdgcn_mfma_f32_32x32x16_bf16(A0, B0, acc[0][0], 0,0,0);
      acc[1][0] = __builtin_amdgcn_mfma_f32_32x32x16_bf16(A1, B0, acc[1][0], 0,0,0);
      acc[0][1] = __builtin_amdgcn_mfma_f32_32x32x16_bf16(A0, B1, acc[0][1], 0,0,0);
      acc[1][1] = __builtin_amdgcn_mfma_f32_32x32x16_bf16(A1, B1, acc[1][1], 0,0,0);
    }

    #pragma unroll
    for (int pq=0; pq<2; ++pq){
      int p = p0 + pq*32 + l31;
      __bf16* out = ubuf + ((size_t)(br*NN + n)*TV + p)*256;
      #pragma unroll
      for (int oq=0; oq<2; ++oq){
        #pragma unroll
        for (int g=0; g<4; ++g){
          int og = os*64 + oq*32 + 8*g + 4*h;
          v4bf pk;
          #pragma unroll
          for (int j=0;j<4;++j) pk[j] = (__bf16)acc[oq][pq][4*g+j];
          *(v4bf*)(out + og) = pk;
        }
      }
    }
  }
}

// ---------- scores v2: MFMA + in-block chunk reduce -> 4KB coalesced partial.
__global__ __launch_bounds__(256) void scores_m2_k(const __bf16* __restrict__ fbuf,
                                                   float* __restrict__ part, int pairbase){
  __shared__ float smp[4][1024];
  int bx = blockIdx.x, n = blockIdx.y, pr = blockIdx.z;
  int tid = threadIdx.x;
  int lane = tid & 63;
  int wave = tid >> 6;
  int chunk = bx*4 + wave;
  int h = lane >> 5, l31 = lane & 31;
  const __bf16* f1 = fbuf + (size_t)(pr*2)*NICTV   + (size_t)n*TV*64;
  const __bf16* f2 = fbuf + (size_t)(pr*2+1)*NICTV + (size_t)n*TV*64;
  int t0 = chunk*4;

  f32x16 acc;
  #pragma unroll
  for (int r=0;r<16;++r) acc[r] = 0.f;

  auto off = [&](int s)->size_t{
    int t = t0 + (s>>2), og = s&3;
    return ((size_t)(t*25 + l31))*64 + og*16 + h*8;
  };
  v8bf A[4], B[4];
  #pragma unroll
  for (int i=0; i<4; ++i){
    size_t o = off(i);
    A[i] = *(const v8bf*)(f1+o); B[i] = *(const v8bf*)(f2+o);
  }
  #pragma unroll
  for (int s=0; s<16; ++s){
    int cur = s & 3;
    v8bf Ac = A[cur], Bc = B[cur];
    if (s+4 < 16){
      size_t o2 = off(s+4);
      A[cur] = *(const v8bf*)(f1+o2);
      B[cur] = *(const v8bf*)(f2+o2);
    }
    acc = __builtin_amdgcn_mfma_f32_32x32x16_bf16(Ac, Bc, acc, 0,0,0);
  }

  #pragma unroll
  for (int r=0; r<16; ++r){
    int row = (r&3) + 8*(r>>2) + 4*h;
    smp[wave][row*32 + l31] = acc[r];
  }
  __syncthreads();
  for (int j = tid; j < 1024; j += 256){
    float s = smp[0][j] + smp[1][j] + smp[2][j] + smp[3][j];
    part[(((size_t)(pairbase+pr)*NN + n)*4 + bx)*1024 + j] = s;
  }
}

// ---------- finalize v3: one thread per (v,w); emits PADDED global aisg
// aisg[n][br][v*28 + w] (w<25 = Aall + softmax-sum; w in 25..27 = 0) so the
// epilogue can read it with wave-uniform addresses (scalar/SMEM path).
__global__ __launch_bounds__(800) void finalize3_k(const float* __restrict__ part,
    const float* __restrict__ Aall, float* __restrict__ aisg){
  __shared__ float smR[25][33];
  int n = blockIdx.x, br = blockIdx.y;
  int w = threadIdx.x;                      // 0..31
  int v = threadIdx.y;                      // 0..24
  const int prs0[3] = {0,3,5}, prs1[3] = {1,6,8}, prs2[3] = {2,4,7};
  const int* prs = (br==0) ? prs0 : (br==1) ? prs1 : prs2;
  float acc = 0.f;
  for (int k=0; k<3; ++k){
    const float* pb = part + ((size_t)prs[k]*NN + n)*4096;
    float s = 0.f;
    if (w < 25){
      s = pb[v*32+w] + pb[1024+v*32+w] + pb[2048+v*32+w] + pb[3072+v*32+w];
      s *= (1.f/4096.f);
    }
    smR[v][w] = s;
    __syncthreads();
    #pragma unroll
    for (int d=16; d>0; d>>=1){
      if (v < d){
        float o = (v+d < 25) ? smR[v+d][w] : -3.4e38f;
        smR[v][w] = fmaxf(smR[v][w], o);
      }
      __syncthreads();
    }
    float mx = smR[0][w];
    __syncthreads();
    float e = __expf(s - mx);
    smR[v][w] = e;
    __syncthreads();
    #pragma unroll
    for (int d=16; d>0; d>>=1){
      if (v < d){
        float o = (v+d < 25) ? smR[v+d][w] : 0.f;
        smR[v][w] += o;
      }
      __syncthreads();
    }
    float sum = smR[0][w];
    __syncthreads();
    acc += e / sum;
  }
  if (w < 28){
    float val = (w < 25) ? (Aall[br*625 + v*25 + w] + acc) : 0.f;
    aisg[((size_t)n*3 + br)*700 + v*28 + w] = val;
  }
}

// ---------- epilogue v3: 2-t register blocking + ais from GLOBAL (uniform
// address -> scalar/SMEM loads, off the LDS pipe). r11 diagnosis: yep was
// LDS-instruction bound (525 broadcast ds_read_b128/thread = 42us/CU).
// grid (32 t2, 16 n), block 256; LDS only for coalesced x/out staging.
__global__ __launch_bounds__(256, 2) void yep3_k(const float* __restrict__ x,
    const float* __restrict__ aisg, const __bf16* __restrict__ ubuf,
    const float* __restrict__ bd, const float* __restrict__ gamma,
    const float* __restrict__ beta, const float* __restrict__ bnm,
    const float* __restrict__ bnv, float* __restrict__ out){
  __shared__ float xs[2][6400];             // 2t x (256 o x 25 w)
  int t2 = blockIdx.x, n = blockIdx.y, o = threadIdx.x;
  int t0 = t2*2;
  // coalesced x-read: linear (dt, oo*25+ww) mapping -> 100B runs
  for (int li=o; li<12800; li+=256){
    int dt = li / 6400, r = li % 6400;
    int oo = r/25, ww = r%25;
    xs[dt][r] = x[(size_t)n*CTV + (size_t)oo*TV + (t0+dt)*25 + ww];
  }
  __syncthreads();
  float y0[28], y1[28];
  #pragma unroll
  for (int w=0;w<28;++w){ y0[w]=0.f; y1[w]=0.f; }
  for (int br=0; br<3; ++br){
    const __bf16* up = ubuf + ((size_t)(br*NN + n)*TV + t0*25)*256 + o;
    float u0[25], u1[25];
    #pragma unroll
    for (int v=0;v<25;++v){
      u0[v] = (float)up[(size_t)v*256];
      u1[v] = (float)up[(size_t)(v+25)*256];
    }
    const float* ab = aisg + ((size_t)n*3 + br)*700;   // wave-uniform base
    for (int v=0; v<25; ++v){
      float a0 = u0[v], a1 = u1[v];
      #pragma unroll
      for (int j=0; j<7; ++j){
        float4 a4 = *(const float4*)(ab + v*28 + 4*j); // uniform -> s_load
        y0[4*j+0] = fmaf(a0, a4.x, y0[4*j+0]);
        y0[4*j+1] = fmaf(a0, a4.y, y0[4*j+1]);
        y0[4*j+2] = fmaf(a0, a4.z, y0[4*j+2]);
        y0[4*j+3] = fmaf(a0, a4.w, y0[4*j+3]);
        y1[4*j+0] = fmaf(a1, a4.x, y1[4*j+0]);
        y1[4*j+1] = fmaf(a1, a4.y, y1[4*j+1]);
        y1[4*j+2] = fmaf(a1, a4.z, y1[4*j+2]);
        y1[4*j+3] = fmaf(a1, a4.w, y1[4*j+3]);
      }
    }
  }
  float bsum = bd[o] + bd[256+o] + bd[512+o];
  float sc = gamma[o] * rsqrtf(bnv[o] + 1e-5f);
  float m  = bnm[o], be = beta[o];
  #pragma unroll
  for (int w=0; w<25; ++w){
    xs[0][o*25+w] = fmaxf((y0[w] + bsum - m)*sc + be + xs[0][o*25+w], 0.f);
    xs[1][o*25+w] = fmaxf((y1[w] + bsum - m)*sc + be + xs[1][o*25+w], 0.f);
  }
  __syncthreads();
  // coalesced write-out
  for (int li=o; li<12800; li+=256){
    int dt = li / 6400, r = li % 6400;
    int oo = r/25, ww = r%25;
    out[(size_t)n*CTV + (size_t)oo*TV + (t0+dt)*25 + ww] = xs[dt][r];
  }
}

extern "C" void kernel_launch(void* const* d_in, const int* in_sizes, int n_in,
                              void* d_out, int out_size, void* d_ws, size_t ws_size,
                              hipStream_t stream) {
  const float* x     = (const float*)d_in[0];
  const float* A     = (const float*)d_in[1];
  const float* PA    = (const float*)d_in[2];
  const float* wa    = (const float*)d_in[3];
  const float* ba    = (const float*)d_in[4];
  const float* wb    = (const float*)d_in[5];
  const float* bb    = (const float*)d_in[6];
  const float* wT1   = (const float*)d_in[7];
  const float* bT1   = (const float*)d_in[8];
  const float* wT2   = (const float*)d_in[9];
  const float* bT2   = (const float*)d_in[10];
  const float* wST11 = (const float*)d_in[11];
  const float* bST11 = (const float*)d_in[12];
  const float* wST12 = (const float*)d_in[13];
  const float* bST12 = (const float*)d_in[14];
  const float* wd    = (const float*)d_in[15];
  const float* bd    = (const float*)d_in[16];
  const float* gamma = (const float*)d_in[17];
  const float* beta  = (const float*)d_in[18];
  const float* bnm   = (const float*)d_in[19];
  const float* bnv   = (const float*)d_in[20];

  char* W = (char*)d_ws;
  float*  Aall = (float*)W;  W += 8192;
  __bf16* zp   = (__bf16*)W; W += 256;       // zero page for OOB staging
  float*  aisg = (float*)W;  W += 135168;    // 16 n x 3 br x 25 v x 28 w f32 (padded)
  __bf16* wabp = (__bf16*)W; W += 196608;    // 6 packed 1x1 convs (wa x3, wb x3)
  __bf16* wScp = (__bf16*)W; W += 131072;    // 4 packed center-tap convs
  __bf16* wT1p = (__bf16*)W; W += 884736;    // 3 packed 9-tap convs
  __bf16* wT2p = (__bf16*)W; W += 884736;
  __bf16* wS1p = (__bf16*)W; W += 294912;    // s=1 only
  __bf16* wS2p = (__bf16*)W; W += 294912;
  __bf16* wdb  = (__bf16*)W; W += 393216;
  __bf16* xt   = (__bf16*)W; W += 13107200;
  char* R = W;               W += 39321600;  // fbuf (10 slices) / ubuf overlay
  float*  part = (float*)W;  W += 2359296;   // 9*16*4*1024 f32 (chunk-reduced)
  __bf16* fbuf = (__bf16*)R;
  __bf16* ubuf = (__bf16*)R;

  // merged prep
  prep_k<<<2443, 256, 0, stream>>>(x, xt, wT1, wT2, wST11, wST12,
                                   wT1p, wT2p, wS1p, wS2p,
                                   wa, wb, wabp, wScp, wd, wdb, A, PA, Aall, zp);

  // phase 1: all "1x1" pairs (A x3, ST-even x2 via packed center-tap) -> pairs 0..4
  {
    ConvPairs cp;
    for (int i=0;i<3;++i){
      cp.wA[i] = wabp + (size_t)i*16384;      cp.wB[i] = wabp + (size_t)(3+i)*16384;
      cp.bA[i] = ba + i*64;                   cp.bB[i] = bb + i*64;
    }
    int evens[2] = {0, 2};
    for (int j=0;j<2;++j){
      int i = evens[j];
      cp.wA[3+j] = wScp + (size_t)j*16384;    cp.wB[3+j] = wScp + (size_t)(2+j)*16384;
      cp.bA[3+j] = bST11 + i*64;              cp.bB[3+j] = bST12 + i*64;
    }
    // LDS: 2 x-bufs (256*32) + A (2*2048) = 20480 elems = 40960 B
    conv15_k<1,4><<<dim3(7,16,5), 512, 40960, stream>>>(xt, cp, zp, fbuf);
    scores_m2_k<<<dim3(4,16,5), 256, 0, stream>>>(fbuf, part, 0);
  }

  // phase 2: all 9-tap pairs (T x3, ST-odd x1) -> pairs 5..8
  {
    ConvPairs cp;
    for (int i=0;i<3;++i){
      cp.wA[i] = wT1p + (size_t)i*147456;  cp.wB[i] = wT2p + (size_t)i*147456;
      cp.bA[i] = bT1 + i*64;               cp.bB[i] = bT2 + i*64;
    }
    cp.wA[3] = wS1p;  cp.wB[3] = wS2p;
    cp.bA[3] = bST11 + 64;  cp.bB[3] = bST12 + 64;
    cp.wA[4] = cp.wA[3]; cp.wB[4] = cp.wB[3]; cp.bA[4] = cp.bA[3]; cp.bB[4] = cp.bB[3];
    // LDS: 2 x-bufs (456*32) + A (2*18432) = 66048 elems = 132096 B
    conv15_k<9,2><<<dim3(7,16,4), 512, 132096, stream>>>(xt, cp, zp, fbuf);
    scores_m2_k<<<dim3(4,16,4), 256, 0, stream>>>(fbuf, part, 5);
  }

  // u GEMM (overwrites fbuf region — dead after phase-2 scores)
  ugemm6_k<<<dim3(25,16), 256, 0, stream>>>(xt, wdb, ubuf);
  // all-pair softmax -> padded aisg (scalar-friendly layout for yep3)
  finalize3_k<<<dim3(16,3), dim3(32,25), 0, stream>>>(part, Aall, aisg);
  // epilogue: 2-t blocking, ais off the LDS pipe
  yep3_k<<<dim3(32,16), 256, 0, stream>>>(x, aisg, ubuf, bd, gamma, beta, bnm, bnv,
                                          (float*)d_out);
}